// Round 3
// baseline (985.548 us; speedup 1.0000x reference)
//
#include <hip/hip_runtime.h>
#include <cstdint>

#define BB 32
#define HH 4096
#define FF 4096
#define EE 8
#define NSLOT 16   // 8 experts x 2 slots of <=16 tokens
#define TSEG 16

#define PB_NCH 16
#define PB_R (HH / PB_NCH)   // 256 rows per passB block
#define PC_NCH 32
#define PC_R (FF / PC_NCH)   // 128 rows per passC block

// ---------------------------------------------------------------- gate ----
__global__ __launch_bounds__(256) void gate_kernel(const float* __restrict__ x,
                                                   const float* __restrict__ Wg,
                                                   float* __restrict__ logits) {
  int b = blockIdx.x;
  int tid = threadIdx.x;
  float acc[EE];
#pragma unroll
  for (int e = 0; e < EE; ++e) acc[e] = 0.f;
  const float* xb = x + (size_t)b * HH;
  for (int h = tid; h < HH; h += 256) {
    float xv = xb[h];
    const float4* wg = (const float4*)(Wg + (size_t)h * EE);
    float4 w0 = wg[0], w1 = wg[1];
    acc[0] = fmaf(xv, w0.x, acc[0]);
    acc[1] = fmaf(xv, w0.y, acc[1]);
    acc[2] = fmaf(xv, w0.z, acc[2]);
    acc[3] = fmaf(xv, w0.w, acc[3]);
    acc[4] = fmaf(xv, w1.x, acc[4]);
    acc[5] = fmaf(xv, w1.y, acc[5]);
    acc[6] = fmaf(xv, w1.z, acc[6]);
    acc[7] = fmaf(xv, w1.w, acc[7]);
  }
#pragma unroll
  for (int off = 32; off > 0; off >>= 1) {
#pragma unroll
    for (int e = 0; e < EE; ++e) acc[e] += __shfl_down(acc[e], off, 64);
  }
  __shared__ float part[4][EE];
  if ((tid & 63) == 0) {
#pragma unroll
    for (int e = 0; e < EE; ++e) part[tid >> 6][e] = acc[e];
  }
  __syncthreads();
  if (tid < EE) {
    logits[(size_t)b * EE + tid] =
        part[0][tid] + part[1][tid] + part[2][tid] + part[3][tid];
  }
}

// --------------------------------------------------------------- route ----
__global__ void route_kernel(const float* __restrict__ logits,
                             int* __restrict__ cnt,
                             int* __restrict__ tok,
                             float* __restrict__ wts) {
  if (threadIdx.x != 0 || blockIdx.x != 0) return;
  int e0[BB], e1[BB];
  float p0[BB], p1[BB];
  for (int b = 0; b < BB; ++b) {
    const float* L = logits + (size_t)b * EE;
    int i0 = 0;
    float v0 = L[0];
    for (int e = 1; e < EE; ++e) {
      float v = L[e];
      if (v > v0) { v0 = v; i0 = e; }
    }
    int i1 = (i0 == 0) ? 1 : 0;
    float v1 = L[i1];
    for (int e = 0; e < EE; ++e) {
      if (e == i0) continue;
      float v = L[e];
      if (v > v1) { v1 = v; i1 = e; }
    }
    float p = 1.f / (1.f + __expf(v1 - v0));
    e0[b] = i0; e1[b] = i1; p0[b] = p; p1[b] = 1.f - p;
  }
  for (int s = 0; s < NSLOT; ++s) {
    cnt[s] = 0;
    for (int t = 0; t < TSEG; ++t) { tok[s * TSEG + t] = 0; wts[s * TSEG + t] = 0.f; }
  }
  for (int e = 0; e < EE; ++e) {
    int c = 0;
    for (int b = 0; b < BB; ++b) {
      float w = 0.f;
      int sel = 0;
      if (e0[b] == e) { w = p0[b]; sel = 1; }
      else if (e1[b] == e) { w = p1[b]; sel = 1; }
      if (sel) {
        int s = e * 2 + (c >> 4);
        int t = c & 15;
        tok[s * TSEG + t] = b;
        wts[s * TSEG + t] = w;
        cnt[s] = t + 1;
        ++c;
      }
    }
  }
}

// -------------------------------------------------------------- buildx ----
__global__ __launch_bounds__(256) void buildx_kernel(const float* __restrict__ x,
                                                     const int* __restrict__ cnt,
                                                     const int* __restrict__ tok,
                                                     float* __restrict__ xseg) {
  int s = blockIdx.y;
  int tid = threadIdx.x;
  int t = tid & 15;
  int hoff = tid >> 4;
  int c = cnt[s];
  int tk = tok[s * TSEG + t];
  bool act = t < c;
  int hbase = blockIdx.x * 256;
#pragma unroll
  for (int i = 0; i < 16; ++i) {
    int h = hbase + i * 16 + hoff;
    float v = act ? x[(size_t)tk * HH + h] : 0.f;
    xseg[((size_t)s * HH + h) * TSEG + t] = v;
  }
}

// ------------------------------------------------- accumulate core -------
// acc[t] += sum_i xs[i][t] * W[i][col4..col4+3], depth-4 prefetch ring.
template <int NT>
__device__ __forceinline__ void accum_rows(const float* __restrict__ wp, int ldw,
                                           const float* __restrict__ xp, int R,
                                           float4* __restrict__ acc) {
#pragma unroll
  for (int t = 0; t < NT; ++t) acc[t] = make_float4(0.f, 0.f, 0.f, 0.f);
  float4 wb[4];
#pragma unroll
  for (int k = 0; k < 4; ++k) wb[k] = *(const float4*)(wp + (size_t)k * ldw);
  for (int i0 = 0; i0 < R - 4; i0 += 4) {
#pragma unroll
    for (int k = 0; k < 4; ++k) {
      const int i = i0 + k;
      float4 wv = wb[k];
      wb[k] = *(const float4*)(wp + (size_t)(i + 4) * ldw);
      const float* xr = xp + (size_t)i * TSEG;
      float xs[NT];
#pragma unroll
      for (int q = 0; q < NT; q += 4) *(float4*)&xs[q] = *(const float4*)(xr + q);
#pragma unroll
      for (int t = 0; t < NT; ++t) {
        acc[t].x = fmaf(xs[t], wv.x, acc[t].x);
        acc[t].y = fmaf(xs[t], wv.y, acc[t].y);
        acc[t].z = fmaf(xs[t], wv.z, acc[t].z);
        acc[t].w = fmaf(xs[t], wv.w, acc[t].w);
      }
    }
  }
#pragma unroll
  for (int k = 0; k < 4; ++k) {
    const int i = R - 4 + k;
    float4 wv = wb[k];
    const float* xr = xp + (size_t)i * TSEG;
    float xs[NT];
#pragma unroll
    for (int q = 0; q < NT; q += 4) *(float4*)&xs[q] = *(const float4*)(xr + q);
#pragma unroll
    for (int t = 0; t < NT; ++t) {
      acc[t].x = fmaf(xs[t], wv.x, acc[t].x);
      acc[t].y = fmaf(xs[t], wv.y, acc[t].y);
      acc[t].z = fmaf(xs[t], wv.z, acc[t].z);
      acc[t].w = fmaf(xs[t], wv.w, acc[t].w);
    }
  }
}

template <int NT>
__device__ __forceinline__ void atomic_seg(float* __restrict__ oseg,
                                           const float4* __restrict__ acc) {
#pragma unroll
  for (int t = 0; t < NT; ++t) {
    atomicAdd(oseg + 0 * TSEG + t, acc[t].x);
    atomicAdd(oseg + 1 * TSEG + t, acc[t].y);
    atomicAdd(oseg + 2 * TSEG + t, acc[t].z);
    atomicAdd(oseg + 3 * TSEG + t, acc[t].w);
  }
}

// --------------------------------------------------------------- passB ----
// 4 waves: w>>1 selects W1/W3, w&1 selects 256-col half. All waves run full
// PB_R rows of this z-chunk; partials via fp32 atomics into h1seg/h3seg.
__global__ __launch_bounds__(256, 4) void passB3_kernel(const float* __restrict__ W1,
                                                        const float* __restrict__ W3,
                                                        const float* __restrict__ xseg,
                                                        float* __restrict__ h1seg,
                                                        float* __restrict__ h3seg,
                                                        const int* __restrict__ cnt) {
  int s = blockIdx.y;
  int c = cnt[s];
  if (c == 0) return;
  int e = s >> 1;
  int tid = threadIdx.x;
  int l = tid & 63;
  int w = tid >> 6;
  int mat = w >> 1;
  int col4 = blockIdx.x * 512 + (w & 1) * 256 + l * 4;
  int row0 = __builtin_amdgcn_readfirstlane(blockIdx.z * PB_R);
  const float* Wm = (mat ? W3 : W1) + (size_t)e * HH * FF + (size_t)row0 * FF + col4;
  const float* xp = xseg + ((size_t)s * HH + row0) * TSEG;
  float* oseg = (mat ? h3seg : h1seg) + ((size_t)s * FF + col4) * TSEG;
  if (c <= 8) {
    float4 acc[8];
    accum_rows<8>(Wm, FF, xp, PB_R, acc);
    atomic_seg<8>(oseg, acc);
  } else {
    float4 acc[16];
    accum_rows<16>(Wm, FF, xp, PB_R, acc);
    atomic_seg<16>(oseg, acc);
  }
}

// ------------------------------------------------------------- combine ----
__global__ __launch_bounds__(256) void silu_combine_kernel(float* __restrict__ h1seg,
                                                           const float* __restrict__ h3seg) {
  size_t i = (size_t)blockIdx.x * 256 + threadIdx.x;  // float4 index
  float4 h1 = ((const float4*)h1seg)[i];
  float4 h3 = ((const float4*)h3seg)[i];
  float4 r;
  r.x = (h1.x / (1.f + __expf(-h1.x))) * h3.x;
  r.y = (h1.y / (1.f + __expf(-h1.y))) * h3.y;
  r.z = (h1.z / (1.f + __expf(-h1.z))) * h3.z;
  r.w = (h1.w / (1.f + __expf(-h1.w))) * h3.w;
  ((float4*)h1seg)[i] = r;
}

// --------------------------------------------------------------- passC ----
// 4 waves split 1024 H-cols; each runs PC_R rows of the f-chunk; weighted
// partials via fp32 atomics straight into out.
template <int NT>
__device__ __forceinline__ void passC_epi(float* __restrict__ out,
                                          const int* __restrict__ tok,
                                          const float* __restrict__ wts,
                                          int s, int c, int col4,
                                          const float4* __restrict__ acc) {
#pragma unroll
  for (int t = 0; t < NT; ++t) {
    if (t < c) {
      int tk = tok[s * TSEG + t];
      float wt = wts[s * TSEG + t];
      float* op = out + (size_t)tk * HH + col4;
      atomicAdd(op + 0, wt * acc[t].x);
      atomicAdd(op + 1, wt * acc[t].y);
      atomicAdd(op + 2, wt * acc[t].z);
      atomicAdd(op + 3, wt * acc[t].w);
    }
  }
}

__global__ __launch_bounds__(256, 4) void passC3_kernel(const float* __restrict__ W2,
                                                        const float* __restrict__ gseg,
                                                        const int* __restrict__ cnt,
                                                        const int* __restrict__ tok,
                                                        const float* __restrict__ wts,
                                                        float* __restrict__ out) {
  int s = blockIdx.y;
  int c = cnt[s];
  if (c == 0) return;
  int e = s >> 1;
  int tid = threadIdx.x;
  int l = tid & 63;
  int w = tid >> 6;
  int col4 = blockIdx.x * 1024 + w * 256 + l * 4;
  int row0 = __builtin_amdgcn_readfirstlane(blockIdx.z * PC_R);
  const float* Wm = W2 + (size_t)e * FF * HH + (size_t)row0 * HH + col4;
  const float* xp = gseg + ((size_t)s * FF + row0) * TSEG;
  if (c <= 8) {
    float4 acc[8];
    accum_rows<8>(Wm, HH, xp, PC_R, acc);
    passC_epi<8>(out, tok, wts, s, c, col4, acc);
  } else {
    float4 acc[16];
    accum_rows<16>(Wm, HH, xp, PC_R, acc);
    passC_epi<16>(out, tok, wts, s, c, col4, acc);
  }
}

// -------------------------------------------------------------- launch ----
extern "C" void kernel_launch(void* const* d_in, const int* in_sizes, int n_in,
                              void* d_out, int out_size, void* d_ws, size_t ws_size,
                              hipStream_t stream) {
  const float* x  = (const float*)d_in[0];
  const float* Wg = (const float*)d_in[1];
  const float* W1 = (const float*)d_in[2];
  const float* W3 = (const float*)d_in[3];
  const float* W2 = (const float*)d_in[4];
  float* out = (float*)d_out;

  char* ws = (char*)d_ws;
  float* logits = (float*)ws;                 // 256 f32
  int*   cnt    = (int*)(ws + 1024);          // 16 i32
  int*   tok    = (int*)(ws + 1088);          // 256 i32
  float* wts    = (float*)(ws + 2112);        // 256 f32
  float* xseg   = (float*)(ws + 4096);                 // 4 MB
  float* h1seg  = xseg + (size_t)NSLOT * HH * TSEG;    // 4 MB
  float* h3seg  = h1seg + (size_t)NSLOT * FF * TSEG;   // 4 MB

  hipMemsetAsync(d_out, 0, (size_t)out_size * sizeof(float), stream);
  hipMemsetAsync(h1seg, 0, (size_t)2 * NSLOT * FF * TSEG * sizeof(float), stream);
  gate_kernel<<<BB, 256, 0, stream>>>(x, Wg, logits);
  route_kernel<<<1, 64, 0, stream>>>(logits, cnt, tok, wts);
  buildx_kernel<<<dim3(HH / 256, NSLOT), 256, 0, stream>>>(x, cnt, tok, xseg);
  passB3_kernel<<<dim3(FF / 512, NSLOT, PB_NCH), 256, 0, stream>>>(W1, W3, xseg, h1seg, h3seg, cnt);
  silu_combine_kernel<<<(NSLOT * FF * TSEG) / (256 * 4), 256, 0, stream>>>(h1seg, h3seg);
  passC3_kernel<<<dim3(HH / 1024, NSLOT, PC_NCH), 256, 0, stream>>>(W2, h1seg, cnt, tok, wts, out);
}

// Round 4
// 504.488 us; speedup vs baseline: 1.9536x; 1.9536x over previous
//
#include <hip/hip_runtime.h>
#include <cstdint>

#define BB 32
#define HH 4096
#define FF 4096
#define EE 8
#define NSLOT 16   // 8 experts x 2 slots of <=16 tokens
#define TSEG 16
#define CH 1024            // rows per LDS chunk
#define NCHK (HH / CH)     // 4 chunks
#define RSTRIDE 33         // padded LDS reduce stride (bank-conflict-free)
#define RSEG (64 * RSTRIDE)

// ---------------------------------------------------------------- gate ----
__global__ __launch_bounds__(256) void gate_kernel(const float* __restrict__ x,
                                                   const float* __restrict__ Wg,
                                                   float* __restrict__ logits) {
  int b = blockIdx.x;
  int tid = threadIdx.x;
  float acc[EE];
#pragma unroll
  for (int e = 0; e < EE; ++e) acc[e] = 0.f;
  const float* xb = x + (size_t)b * HH;
  for (int h = tid; h < HH; h += 256) {
    float xv = xb[h];
    const float4* wg = (const float4*)(Wg + (size_t)h * EE);
    float4 w0 = wg[0], w1 = wg[1];
    acc[0] = fmaf(xv, w0.x, acc[0]);
    acc[1] = fmaf(xv, w0.y, acc[1]);
    acc[2] = fmaf(xv, w0.z, acc[2]);
    acc[3] = fmaf(xv, w0.w, acc[3]);
    acc[4] = fmaf(xv, w1.x, acc[4]);
    acc[5] = fmaf(xv, w1.y, acc[5]);
    acc[6] = fmaf(xv, w1.z, acc[6]);
    acc[7] = fmaf(xv, w1.w, acc[7]);
  }
#pragma unroll
  for (int off = 32; off > 0; off >>= 1) {
#pragma unroll
    for (int e = 0; e < EE; ++e) acc[e] += __shfl_down(acc[e], off, 64);
  }
  __shared__ float part[4][EE];
  if ((tid & 63) == 0) {
#pragma unroll
    for (int e = 0; e < EE; ++e) part[tid >> 6][e] = acc[e];
  }
  __syncthreads();
  if (tid < EE) {
    logits[(size_t)b * EE + tid] =
        part[0][tid] + part[1][tid] + part[2][tid] + part[3][tid];
  }
}

// --------------------------------------------------------------- route ----
__global__ void route_kernel(const float* __restrict__ logits,
                             int* __restrict__ cnt,
                             int* __restrict__ tok,
                             float* __restrict__ wts) {
  if (threadIdx.x != 0 || blockIdx.x != 0) return;
  int e0[BB], e1[BB];
  float p0[BB], p1[BB];
  for (int b = 0; b < BB; ++b) {
    const float* L = logits + (size_t)b * EE;
    int i0 = 0;
    float v0 = L[0];
    for (int e = 1; e < EE; ++e) {
      float v = L[e];
      if (v > v0) { v0 = v; i0 = e; }
    }
    int i1 = (i0 == 0) ? 1 : 0;
    float v1 = L[i1];
    for (int e = 0; e < EE; ++e) {
      if (e == i0) continue;
      float v = L[e];
      if (v > v1) { v1 = v; i1 = e; }
    }
    float p = 1.f / (1.f + __expf(v1 - v0));
    e0[b] = i0; e1[b] = i1; p0[b] = p; p1[b] = 1.f - p;
  }
  for (int s = 0; s < NSLOT; ++s) {
    cnt[s] = 0;
    for (int t = 0; t < TSEG; ++t) { tok[s * TSEG + t] = 0; wts[s * TSEG + t] = 0.f; }
  }
  for (int e = 0; e < EE; ++e) {
    int c = 0;
    for (int b = 0; b < BB; ++b) {
      float w = 0.f;
      int sel = 0;
      if (e0[b] == e) { w = p0[b]; sel = 1; }
      else if (e1[b] == e) { w = p1[b]; sel = 1; }
      if (sel) {
        int s = e * 2 + (c >> 4);
        int t = c & 15;
        tok[s * TSEG + t] = b;
        wts[s * TSEG + t] = w;
        cnt[s] = t + 1;
        ++c;
      }
    }
  }
}

// -------------------------------------------------------------- buildx ----
__global__ __launch_bounds__(256) void buildx_kernel(const float* __restrict__ x,
                                                     const int* __restrict__ cnt,
                                                     const int* __restrict__ tok,
                                                     float* __restrict__ xseg) {
  int s = blockIdx.y;
  int tid = threadIdx.x;
  int t = tid & 15;
  int hoff = tid >> 4;
  int c = cnt[s];
  int tk = tok[s * TSEG + t];
  bool act = t < c;
  int hbase = blockIdx.x * 256;
#pragma unroll
  for (int i = 0; i < 16; ++i) {
    int h = hbase + i * 16 + hoff;
    float v = act ? x[(size_t)tk * HH + h] : 0.f;
    xseg[((size_t)s * HH + h) * TSEG + t] = v;
  }
}

// --------------------------------------- ring-pipelined row accumulate ----
// Consume-oldest depth-16 float2 weight ring (vmcnt only); x from LDS
// (lgkmcnt) so consuming x never drains the weight queue. R rows, static
// indices throughout (no scratch).
__device__ __forceinline__ void fma_row(float2* __restrict__ acc,
                                        const float* __restrict__ xr, float2 wv) {
  float xs[TSEG];
#pragma unroll
  for (int q = 0; q < TSEG; q += 4) *(float4*)&xs[q] = *(const float4*)(xr + q);
#pragma unroll
  for (int t = 0; t < TSEG; ++t) {
    acc[t].x = fmaf(xs[t], wv.x, acc[t].x);
    acc[t].y = fmaf(xs[t], wv.y, acc[t].y);
  }
}

template <int R>
__device__ __forceinline__ void accum_chunk(float2* __restrict__ acc,
                                            const float* __restrict__ wrow, int ldw,
                                            const float* __restrict__ xrow) {
  float2 ring[16];
#pragma unroll
  for (int k = 0; k < 16; ++k) ring[k] = *(const float2*)(wrow + (size_t)k * ldw);
  for (int i0 = 0; i0 + 16 < R; i0 += 16) {
#pragma unroll
    for (int k = 0; k < 16; ++k) {
      float2 wv = ring[k];
      ring[k] = *(const float2*)(wrow + (size_t)(i0 + 16 + k) * ldw);
      fma_row(acc, xrow + (size_t)(i0 + k) * TSEG, wv);
    }
  }
#pragma unroll
  for (int k = 0; k < 16; ++k)
    fma_row(acc, xrow + (size_t)(R - 16 + k) * TSEG, ring[k]);
}

// --------------------------------------------------------------- passB ----
// Block owns 128 f-cols x all 4096 h-rows for BOTH W1,W3. 4 waves =
// (mat, row-half). x chunks staged in LDS. No atomics: LDS reduce + store.
__global__ __launch_bounds__(256) void passB4_kernel(const float* __restrict__ W1,
                                                     const float* __restrict__ W3,
                                                     const float* __restrict__ xseg,
                                                     float* __restrict__ h1seg,
                                                     float* __restrict__ h3seg,
                                                     const int* __restrict__ cnt) {
  int s = blockIdx.y;
  if (cnt[s] == 0) return;
  int e = s >> 1;
  int tid = threadIdx.x;
  int l = tid & 63;
  int w = tid >> 6;
  int mat = w >> 1;
  int rh = w & 1;
  int colbase = blockIdx.x * 128;
  const float* Wbase = (mat ? W3 : W1) + (size_t)e * HH * FF + colbase + 2 * l;
  const float* xsrc = xseg + (size_t)s * HH * TSEG;
  __shared__ float lx[CH * TSEG];  // 64 KB
  float2 acc[TSEG];
#pragma unroll
  for (int t = 0; t < TSEG; ++t) acc[t] = make_float2(0.f, 0.f);
  for (int ch = 0; ch < NCHK; ++ch) {
    int z0 = ch * CH;
    __syncthreads();
    {
      const float4* src = (const float4*)(xsrc + (size_t)z0 * TSEG);
      float4* dst = (float4*)lx;
#pragma unroll
      for (int k = 0; k < 16; ++k) dst[k * 256 + tid] = src[k * 256 + tid];
    }
    __syncthreads();
    accum_chunk<512>(acc, Wbase + (size_t)(z0 + rh * 512) * FF, FF,
                     lx + (size_t)(rh * 512) * TSEG);
  }
  // cross-row-half reduce per mat, then single-owner store
  __syncthreads();
  float* red = lx;  // 4 x RSEG floats = 33.8 KB
#pragma unroll
  for (int t = 0; t < TSEG; ++t) {
    red[w * RSEG + l * RSTRIDE + 2 * t] = acc[t].x;
    red[w * RSEG + l * RSTRIDE + 2 * t + 1] = acc[t].y;
  }
  __syncthreads();
  {
    int m = tid >> 7;           // matrix
    int col_off = tid & 127;    // column within block
    int lp = col_off >> 1;
    int cc = col_off & 1;
    float* seg = (m ? h3seg : h1seg) + ((size_t)s * FF + colbase + col_off) * TSEG;
    float v[TSEG];
#pragma unroll
    for (int t = 0; t < TSEG; ++t) {
      int idx = lp * RSTRIDE + 2 * t + cc;
      v[t] = red[(2 * m) * RSEG + idx] + red[(2 * m + 1) * RSEG + idx];
    }
#pragma unroll
    for (int q = 0; q < TSEG; q += 4) *(float4*)(seg + q) = *(const float4*)&v[q];
  }
}

// --------------------------------------------------------------- passC ----
// Block owns 128 h-cols x all 4096 f-rows of W2. 4 waves = row-quarters.
// Staging fuses silu(h1)*h3. Epilogue: 4-way LDS reduce + weighted atomics.
__global__ __launch_bounds__(256) void passC4_kernel(const float* __restrict__ W2,
                                                     const float* __restrict__ h1seg,
                                                     const float* __restrict__ h3seg,
                                                     const int* __restrict__ cnt,
                                                     const int* __restrict__ tok,
                                                     const float* __restrict__ wts,
                                                     float* __restrict__ out) {
  int s = blockIdx.y;
  int c = cnt[s];
  if (c == 0) return;
  int e = s >> 1;
  int tid = threadIdx.x;
  int l = tid & 63;
  int w = tid >> 6;
  int colbase = blockIdx.x * 128;
  const float* Wbase = W2 + (size_t)e * FF * HH + colbase + 2 * l;
  __shared__ float lg[CH * TSEG];  // 64 KB
  __shared__ int stok[TSEG];
  __shared__ float swt[TSEG];
  if (tid < TSEG) {
    stok[tid] = tok[s * TSEG + tid];
    swt[tid] = wts[s * TSEG + tid];
  }
  float2 acc[TSEG];
#pragma unroll
  for (int t = 0; t < TSEG; ++t) acc[t] = make_float2(0.f, 0.f);
  for (int ch = 0; ch < NCHK; ++ch) {
    int z0 = ch * CH;
    __syncthreads();
    {
      const float4* h1p = (const float4*)(h1seg + ((size_t)s * FF + z0) * TSEG);
      const float4* h3p = (const float4*)(h3seg + ((size_t)s * FF + z0) * TSEG);
      float4* dst = (float4*)lg;
#pragma unroll
      for (int k = 0; k < 16; ++k) {
        float4 a = h1p[k * 256 + tid];
        float4 b = h3p[k * 256 + tid];
        float4 g;
        g.x = (a.x / (1.f + __expf(-a.x))) * b.x;
        g.y = (a.y / (1.f + __expf(-a.y))) * b.y;
        g.z = (a.z / (1.f + __expf(-a.z))) * b.z;
        g.w = (a.w / (1.f + __expf(-a.w))) * b.w;
        dst[k * 256 + tid] = g;
      }
    }
    __syncthreads();
    accum_chunk<256>(acc, Wbase + (size_t)(z0 + w * 256) * HH, HH,
                     lg + (size_t)(w * 256) * TSEG);
  }
  // 4-way reduce + weighted atomic scatter
  __syncthreads();
  float* red = lg;
#pragma unroll
  for (int t = 0; t < TSEG; ++t) {
    red[w * RSEG + l * RSTRIDE + 2 * t] = acc[t].x;
    red[w * RSEG + l * RSTRIDE + 2 * t + 1] = acc[t].y;
  }
  __syncthreads();
  {
    int col_off = tid >> 1;
    int lp = col_off >> 1;
    int cc = col_off & 1;
    int tbase = (tid & 1) * 8;
    float* op = out + colbase + col_off;
#pragma unroll
    for (int j = 0; j < 8; ++j) {
      int t = tbase + j;
      if (t < c) {
        int idx = lp * RSTRIDE + 2 * t + cc;
        float y = red[idx] + red[RSEG + idx] + red[2 * RSEG + idx] + red[3 * RSEG + idx];
        atomicAdd(op + (size_t)stok[t] * HH, swt[t] * y);
      }
    }
  }
}

// -------------------------------------------------------------- launch ----
extern "C" void kernel_launch(void* const* d_in, const int* in_sizes, int n_in,
                              void* d_out, int out_size, void* d_ws, size_t ws_size,
                              hipStream_t stream) {
  const float* x  = (const float*)d_in[0];
  const float* Wg = (const float*)d_in[1];
  const float* W1 = (const float*)d_in[2];
  const float* W3 = (const float*)d_in[3];
  const float* W2 = (const float*)d_in[4];
  float* out = (float*)d_out;

  char* ws = (char*)d_ws;
  float* logits = (float*)ws;                 // 256 f32
  int*   cnt    = (int*)(ws + 1024);          // 16 i32
  int*   tok    = (int*)(ws + 1088);          // 256 i32
  float* wts    = (float*)(ws + 2112);        // 256 f32
  float* xseg   = (float*)(ws + 4096);                 // 4 MB
  float* h1seg  = xseg + (size_t)NSLOT * HH * TSEG;    // 4 MB
  float* h3seg  = h1seg + (size_t)NSLOT * FF * TSEG;   // 4 MB

  hipMemsetAsync(d_out, 0, (size_t)out_size * sizeof(float), stream);
  gate_kernel<<<BB, 256, 0, stream>>>(x, Wg, logits);
  route_kernel<<<1, 64, 0, stream>>>(logits, cnt, tok, wts);
  buildx_kernel<<<dim3(HH / 256, NSLOT), 256, 0, stream>>>(x, cnt, tok, xseg);
  passB4_kernel<<<dim3(FF / 128, NSLOT), 256, 0, stream>>>(W1, W3, xseg, h1seg, h3seg, cnt);
  passC4_kernel<<<dim3(HH / 128, NSLOT), 256, 0, stream>>>(W2, h1seg, h3seg, cnt, tok, wts, out);
}

// Round 5
// 419.338 us; speedup vs baseline: 2.3502x; 1.2031x over previous
//
#include <hip/hip_runtime.h>
#include <cstdint>

#define BB 32
#define HH 4096
#define FF 4096
#define EE 8
#define NSLOT 16   // 8 experts x 2 slots of <=16 tokens
#define TSEG 16

// ---------------------------------------------------------------- gate ----
__global__ __launch_bounds__(256) void gate_kernel(const float* __restrict__ x,
                                                   const float* __restrict__ Wg,
                                                   float* __restrict__ logits) {
  int b = blockIdx.x;
  int tid = threadIdx.x;
  float acc[EE];
#pragma unroll
  for (int e = 0; e < EE; ++e) acc[e] = 0.f;
  const float* xb = x + (size_t)b * HH;
  for (int h = tid; h < HH; h += 256) {
    float xv = xb[h];
    const float4* wg = (const float4*)(Wg + (size_t)h * EE);
    float4 w0 = wg[0], w1 = wg[1];
    acc[0] = fmaf(xv, w0.x, acc[0]);
    acc[1] = fmaf(xv, w0.y, acc[1]);
    acc[2] = fmaf(xv, w0.z, acc[2]);
    acc[3] = fmaf(xv, w0.w, acc[3]);
    acc[4] = fmaf(xv, w1.x, acc[4]);
    acc[5] = fmaf(xv, w1.y, acc[5]);
    acc[6] = fmaf(xv, w1.z, acc[6]);
    acc[7] = fmaf(xv, w1.w, acc[7]);
  }
#pragma unroll
  for (int off = 32; off > 0; off >>= 1) {
#pragma unroll
    for (int e = 0; e < EE; ++e) acc[e] += __shfl_down(acc[e], off, 64);
  }
  __shared__ float part[4][EE];
  if ((tid & 63) == 0) {
#pragma unroll
    for (int e = 0; e < EE; ++e) part[tid >> 6][e] = acc[e];
  }
  __syncthreads();
  if (tid < EE) {
    logits[(size_t)b * EE + tid] =
        part[0][tid] + part[1][tid] + part[2][tid] + part[3][tid];
  }
}

// --------------------------------------------------------------- route ----
__global__ void route_kernel(const float* __restrict__ logits,
                             int* __restrict__ cnt,
                             int* __restrict__ tok,
                             float* __restrict__ wts) {
  if (threadIdx.x != 0 || blockIdx.x != 0) return;
  int e0[BB], e1[BB];
  float p0[BB], p1[BB];
  for (int b = 0; b < BB; ++b) {
    const float* L = logits + (size_t)b * EE;
    int i0 = 0;
    float v0 = L[0];
    for (int e = 1; e < EE; ++e) {
      float v = L[e];
      if (v > v0) { v0 = v; i0 = e; }
    }
    int i1 = (i0 == 0) ? 1 : 0;
    float v1 = L[i1];
    for (int e = 0; e < EE; ++e) {
      if (e == i0) continue;
      float v = L[e];
      if (v > v1) { v1 = v; i1 = e; }
    }
    float p = 1.f / (1.f + __expf(v1 - v0));
    e0[b] = i0; e1[b] = i1; p0[b] = p; p1[b] = 1.f - p;
  }
  for (int s = 0; s < NSLOT; ++s) {
    cnt[s] = 0;
    for (int t = 0; t < TSEG; ++t) { tok[s * TSEG + t] = 0; wts[s * TSEG + t] = 0.f; }
  }
  for (int e = 0; e < EE; ++e) {
    int c = 0;
    for (int b = 0; b < BB; ++b) {
      float w = 0.f;
      int sel = 0;
      if (e0[b] == e) { w = p0[b]; sel = 1; }
      else if (e1[b] == e) { w = p1[b]; sel = 1; }
      if (sel) {
        int s = e * 2 + (c >> 4);
        int t = c & 15;
        tok[s * TSEG + t] = b;
        wts[s * TSEG + t] = w;
        cnt[s] = t + 1;
        ++c;
      }
    }
  }
}

// -------------------------------------------------------------- buildx ----
__global__ __launch_bounds__(256) void buildx_kernel(const float* __restrict__ x,
                                                     const int* __restrict__ cnt,
                                                     const int* __restrict__ tok,
                                                     float* __restrict__ xseg) {
  int s = blockIdx.y;
  int tid = threadIdx.x;
  int t = tid & 15;
  int hoff = tid >> 4;
  int c = cnt[s];
  int tk = tok[s * TSEG + t];
  bool act = t < c;
  int hbase = blockIdx.x * 256;
#pragma unroll
  for (int i = 0; i < 16; ++i) {
    int h = hbase + i * 16 + hoff;
    float v = act ? x[(size_t)tk * HH + h] : 0.f;
    xseg[((size_t)s * HH + h) * TSEG + t] = v;
  }
}

// ----------------------------------------------------------- core math ----
template <int NT>
__device__ __forceinline__ void fma_rowT(float4* __restrict__ acc,
                                         const float* __restrict__ xr, float4 wv) {
  float xs[NT];
#pragma unroll
  for (int q = 0; q < NT; q += 4) *(float4*)&xs[q] = *(const float4*)(xr + q);
#pragma unroll
  for (int t = 0; t < NT; ++t) {
    acc[t].x = fmaf(xs[t], wv.x, acc[t].x);
    acc[t].y = fmaf(xs[t], wv.y, acc[t].y);
    acc[t].z = fmaf(xs[t], wv.z, acc[t].z);
    acc[t].w = fmaf(xs[t], wv.w, acc[t].w);
  }
}

// 256 rows, depth-8 float4 weight ring (vmcnt only); x from LDS (lgkmcnt).
template <int NT>
__device__ __forceinline__ void accum_chunk256(float4* __restrict__ acc,
                                               const float* __restrict__ wp,
                                               const float* __restrict__ xr) {
  float4 ring[8];
#pragma unroll
  for (int k = 0; k < 8; ++k) ring[k] = *(const float4*)(wp + (size_t)k * 4096);
  for (int i0 = 0; i0 + 8 < 256; i0 += 8) {
#pragma unroll
    for (int k = 0; k < 8; ++k) {
      float4 wv = ring[k];
      ring[k] = *(const float4*)(wp + (size_t)(i0 + 8 + k) * 4096);
      fma_rowT<NT>(acc, xr + (size_t)(i0 + k) * NT, wv);
    }
  }
#pragma unroll
  for (int k = 0; k < 8; ++k)
    fma_rowT<NT>(acc, xr + (size_t)(248 + k) * NT, ring[k]);
}

// Stage CH=1024 rows x NT floats from [row][16]-strided src into packed LDS.
template <int NT>
__device__ __forceinline__ void stageT(float* __restrict__ lx,
                                       const float* __restrict__ src, int tid) {
  const float4* s4 = (const float4*)src;
  float4* d4 = (float4*)lx;
#pragma unroll
  for (int k = 0; k < NT; ++k) {
    int q = k * 256 + tid;
    int row = q / (NT / 4);
    int part = q & ((NT / 4) - 1);
    d4[q] = s4[row * 4 + part];
  }
}

// 4-wave reduce through LDS ([t][w][lane] float4 layout, conflict-free).
template <int NT>
__device__ __forceinline__ void reduce4(float* __restrict__ lx,
                                        const float4* __restrict__ acc,
                                        float* __restrict__ v, int tid) {
  int l = tid & 63;
  int w = tid >> 6;
  __syncthreads();
  float4* red = (float4*)lx;
#pragma unroll
  for (int t = 0; t < NT; ++t) red[(t * 4 + w) * 64 + l] = acc[t];
  __syncthreads();
  int lane = tid >> 2;
  int sub = tid & 3;
#pragma unroll
  for (int t = 0; t < NT; ++t) {
    float sum = 0.f;
#pragma unroll
    for (int w4 = 0; w4 < 4; ++w4)
      sum += lx[(((t * 4 + w4) * 64 + lane) << 2) + sub];
    v[t] = sum;
  }
}

// --------------------------------------------------------------- passB ----
// Block: one matrix (z), 256 f-cols, all 4096 h-rows (4 waves x interleaved
// 256-row pieces per 1024-row staged chunk). No atomics.
template <int NT>
__device__ __forceinline__ void passB_body(const float* __restrict__ Wm,
                                           const float* __restrict__ xsrc,
                                           float* __restrict__ segbase,
                                           float* __restrict__ lx, int tid) {
  int l = tid & 63;
  int w = tid >> 6;
  float4 acc[NT];
#pragma unroll
  for (int t = 0; t < NT; ++t) acc[t] = make_float4(0.f, 0.f, 0.f, 0.f);
  for (int ch = 0; ch < 4; ++ch) {
    __syncthreads();
    stageT<NT>(lx, xsrc + (size_t)(ch * 1024) * TSEG, tid);
    __syncthreads();
    accum_chunk256<NT>(acc, Wm + (size_t)(ch * 1024 + w * 256) * FF + l * 4,
                       lx + (size_t)(w * 256) * NT);
  }
  float v[TSEG];
#pragma unroll
  for (int t = 0; t < TSEG; ++t) v[t] = 0.f;
  reduce4<NT>(lx, acc, v, tid);
  float* seg = segbase + (size_t)tid * TSEG;
#pragma unroll
  for (int q = 0; q < TSEG; q += 4) *(float4*)(seg + q) = *(const float4*)&v[q];
}

__global__ __launch_bounds__(256) void passB5_kernel(const float* __restrict__ W1,
                                                     const float* __restrict__ W3,
                                                     const float* __restrict__ xseg,
                                                     float* __restrict__ h1seg,
                                                     float* __restrict__ h3seg,
                                                     const int* __restrict__ cnt) {
  __shared__ float lx[1024 * TSEG];  // 64 KB
  int s = blockIdx.y;
  int c = cnt[s];
  if (c == 0) return;
  int e = s >> 1;
  int mat = blockIdx.z;
  int colbase = blockIdx.x * 256;
  const float* Wm = (mat ? W3 : W1) + (size_t)e * HH * FF + colbase;
  const float* xsrc = xseg + (size_t)s * HH * TSEG;
  float* segbase = (mat ? h3seg : h1seg) + ((size_t)s * FF + colbase) * TSEG;
  if (c <= 8)
    passB_body<8>(Wm, xsrc, segbase, lx, threadIdx.x);
  else
    passB_body<16>(Wm, xsrc, segbase, lx, threadIdx.x);
}

// ------------------------------------------------------------- combine ----
__global__ __launch_bounds__(256) void silu_combine_kernel(float* __restrict__ h1seg,
                                                           const float* __restrict__ h3seg) {
  size_t i = (size_t)blockIdx.x * 256 + threadIdx.x;  // float4 index
  float4 h1 = ((const float4*)h1seg)[i];
  float4 h3 = ((const float4*)h3seg)[i];
  float4 r;
  r.x = (h1.x / (1.f + __expf(-h1.x))) * h3.x;
  r.y = (h1.y / (1.f + __expf(-h1.y))) * h3.y;
  r.z = (h1.z / (1.f + __expf(-h1.z))) * h3.z;
  r.w = (h1.w / (1.f + __expf(-h1.w))) * h3.w;
  ((float4*)h1seg)[i] = r;
}

// --------------------------------------------------------------- passC ----
// Block: 256 h-cols, rows [z*2048, +2048) of W2 (2 staged chunks). Epilogue:
// reduce + weighted atomics into out (<=4 contributions per element).
template <int NT>
__device__ __forceinline__ void passC_body(const float* __restrict__ Wm,
                                           const float* __restrict__ gsrc,
                                           float* __restrict__ out,
                                           const int* __restrict__ stok,
                                           const float* __restrict__ swt,
                                           int c, int colbase,
                                           float* __restrict__ lx, int tid) {
  int l = tid & 63;
  int w = tid >> 6;
  float4 acc[NT];
#pragma unroll
  for (int t = 0; t < NT; ++t) acc[t] = make_float4(0.f, 0.f, 0.f, 0.f);
  for (int ch = 0; ch < 2; ++ch) {
    __syncthreads();
    stageT<NT>(lx, gsrc + (size_t)(ch * 1024) * TSEG, tid);
    __syncthreads();
    accum_chunk256<NT>(acc, Wm + (size_t)(ch * 1024 + w * 256) * HH + l * 4,
                       lx + (size_t)(w * 256) * NT);
  }
  float v[NT];
  reduce4<NT>(lx, acc, v, tid);
  float* op = out + colbase + tid;
#pragma unroll
  for (int t = 0; t < NT; ++t) {
    if (t < c) atomicAdd(op + (size_t)stok[t] * HH, swt[t] * v[t]);
  }
}

__global__ __launch_bounds__(256) void passC5_kernel(const float* __restrict__ W2,
                                                     const float* __restrict__ gseg,
                                                     const int* __restrict__ cnt,
                                                     const int* __restrict__ tok,
                                                     const float* __restrict__ wts,
                                                     float* __restrict__ out) {
  __shared__ float lx[1024 * TSEG];  // 64 KB
  __shared__ int stok[TSEG];
  __shared__ float swt[TSEG];
  int s = blockIdx.y;
  int c = cnt[s];
  if (c == 0) return;
  int e = s >> 1;
  int z = blockIdx.z;
  int colbase = blockIdx.x * 256;
  if (threadIdx.x < TSEG) {
    stok[threadIdx.x] = tok[s * TSEG + threadIdx.x];
    swt[threadIdx.x] = wts[s * TSEG + threadIdx.x];
  }
  const float* Wm = W2 + (size_t)e * FF * HH + (size_t)(z * 2048) * HH + colbase;
  const float* gsrc = gseg + ((size_t)s * FF + z * 2048) * TSEG;
  if (c <= 8)
    passC_body<8>(Wm, gsrc, out, stok, swt, c, colbase, lx, threadIdx.x);
  else
    passC_body<16>(Wm, gsrc, out, stok, swt, c, colbase, lx, threadIdx.x);
}

// -------------------------------------------------------------- launch ----
extern "C" void kernel_launch(void* const* d_in, const int* in_sizes, int n_in,
                              void* d_out, int out_size, void* d_ws, size_t ws_size,
                              hipStream_t stream) {
  const float* x  = (const float*)d_in[0];
  const float* Wg = (const float*)d_in[1];
  const float* W1 = (const float*)d_in[2];
  const float* W3 = (const float*)d_in[3];
  const float* W2 = (const float*)d_in[4];
  float* out = (float*)d_out;

  char* ws = (char*)d_ws;
  float* logits = (float*)ws;                 // 256 f32
  int*   cnt    = (int*)(ws + 1024);          // 16 i32
  int*   tok    = (int*)(ws + 1088);          // 256 i32
  float* wts    = (float*)(ws + 2112);        // 256 f32
  float* xseg   = (float*)(ws + 4096);                 // 4 MB
  float* h1seg  = xseg + (size_t)NSLOT * HH * TSEG;    // 4 MB
  float* h3seg  = h1seg + (size_t)NSLOT * FF * TSEG;   // 4 MB

  hipMemsetAsync(d_out, 0, (size_t)out_size * sizeof(float), stream);
  gate_kernel<<<BB, 256, 0, stream>>>(x, Wg, logits);
  route_kernel<<<1, 64, 0, stream>>>(logits, cnt, tok, wts);
  buildx_kernel<<<dim3(HH / 256, NSLOT), 256, 0, stream>>>(x, cnt, tok, xseg);
  passB5_kernel<<<dim3(FF / 256, NSLOT, 2), 256, 0, stream>>>(W1, W3, xseg, h1seg, h3seg, cnt);
  silu_combine_kernel<<<(NSLOT * FF * TSEG) / (256 * 4), 256, 0, stream>>>(h1seg, h3seg);
  passC5_kernel<<<dim3(HH / 256, NSLOT, 2), 256, 0, stream>>>(W2, h1seg, cnt, tok, wts, out);
}

// Round 6
// 403.163 us; speedup vs baseline: 2.4445x; 1.0401x over previous
//
#include <hip/hip_runtime.h>
#include <cstdint>

#define BB 32
#define HH 4096
#define FF 4096
#define EE 8
#define NSLOT 16   // 8 experts x 2 slots of <=16 tokens
#define TSEG 16

// ---------------------------------------------------------------- gate ----
__global__ __launch_bounds__(256) void gate_kernel(const float* __restrict__ x,
                                                   const float* __restrict__ Wg,
                                                   float* __restrict__ logits) {
  int b = blockIdx.x;
  int tid = threadIdx.x;
  float acc[EE];
#pragma unroll
  for (int e = 0; e < EE; ++e) acc[e] = 0.f;
  const float* xb = x + (size_t)b * HH;
  for (int h = tid; h < HH; h += 256) {
    float xv = xb[h];
    const float4* wg = (const float4*)(Wg + (size_t)h * EE);
    float4 w0 = wg[0], w1 = wg[1];
    acc[0] = fmaf(xv, w0.x, acc[0]);
    acc[1] = fmaf(xv, w0.y, acc[1]);
    acc[2] = fmaf(xv, w0.z, acc[2]);
    acc[3] = fmaf(xv, w0.w, acc[3]);
    acc[4] = fmaf(xv, w1.x, acc[4]);
    acc[5] = fmaf(xv, w1.y, acc[5]);
    acc[6] = fmaf(xv, w1.z, acc[6]);
    acc[7] = fmaf(xv, w1.w, acc[7]);
  }
#pragma unroll
  for (int off = 32; off > 0; off >>= 1) {
#pragma unroll
    for (int e = 0; e < EE; ++e) acc[e] += __shfl_down(acc[e], off, 64);
  }
  __shared__ float part[4][EE];
  if ((tid & 63) == 0) {
#pragma unroll
    for (int e = 0; e < EE; ++e) part[tid >> 6][e] = acc[e];
  }
  __syncthreads();
  if (tid < EE) {
    logits[(size_t)b * EE + tid] =
        part[0][tid] + part[1][tid] + part[2][tid] + part[3][tid];
  }
}

// --------------------------------------------------------------- route ----
__global__ void route_kernel(const float* __restrict__ logits,
                             int* __restrict__ cnt,
                             int* __restrict__ tok,
                             float* __restrict__ wts,
                             int* __restrict__ ord) {
  if (threadIdx.x != 0 || blockIdx.x != 0) return;
  int e0[BB], e1[BB];
  float p0[BB], p1[BB];
  for (int b = 0; b < BB; ++b) {
    const float* L = logits + (size_t)b * EE;
    int i0 = 0;
    float v0 = L[0];
    for (int e = 1; e < EE; ++e) {
      float v = L[e];
      if (v > v0) { v0 = v; i0 = e; }
    }
    int i1 = (i0 == 0) ? 1 : 0;
    float v1 = L[i1];
    for (int e = 0; e < EE; ++e) {
      if (e == i0) continue;
      float v = L[e];
      if (v > v1) { v1 = v; i1 = e; }
    }
    float p = 1.f / (1.f + __expf(v1 - v0));
    e0[b] = i0; e1[b] = i1; p0[b] = p; p1[b] = 1.f - p;
  }
  for (int s = 0; s < NSLOT; ++s) {
    cnt[s] = 0;
    for (int t = 0; t < TSEG; ++t) { tok[s * TSEG + t] = 0; wts[s * TSEG + t] = 0.f; }
  }
  for (int e = 0; e < EE; ++e) {
    int c = 0;
    for (int b = 0; b < BB; ++b) {
      float w = 0.f;
      int sel = 0;
      if (e0[b] == e) { w = p0[b]; sel = 1; }
      else if (e1[b] == e) { w = p1[b]; sel = 1; }
      if (sel) {
        int s = e * 2 + (c >> 4);
        int t = c & 15;
        tok[s * TSEG + t] = b;
        wts[s * TSEG + t] = w;
        cnt[s] = t + 1;
        ++c;
      }
    }
  }
  // compact: active slots first (so active blocks dispatch first)
  int na = 0;
  for (int s = 0; s < NSLOT; ++s) if (cnt[s] > 0) ord[na++] = s;
  for (int s = 0; s < NSLOT; ++s) if (cnt[s] == 0) ord[na++] = s;
}

// -------------------------------------------------------------- buildx ----
__global__ __launch_bounds__(256) void buildx_kernel(const float* __restrict__ x,
                                                     const int* __restrict__ cnt,
                                                     const int* __restrict__ tok,
                                                     float* __restrict__ xseg) {
  int s = blockIdx.y;
  int c = cnt[s];
  if (c == 0) return;
  int tid = threadIdx.x;
  int t = tid & 15;
  int hoff = tid >> 4;
  int tk = tok[s * TSEG + t];
  bool act = t < c;
  int hbase = blockIdx.x * 256;
#pragma unroll
  for (int i = 0; i < 16; ++i) {
    int h = hbase + i * 16 + hoff;
    float v = act ? x[(size_t)tk * HH + h] : 0.f;
    xseg[((size_t)s * HH + h) * TSEG + t] = v;
  }
}

// ----------------------------------------------------------- core math ----
template <int NT>
__device__ __forceinline__ void fma_row2(float2* __restrict__ acc,
                                         const float* __restrict__ xr, float2 wv) {
  float xs[NT];
#pragma unroll
  for (int q = 0; q < NT; q += 4) *(float4*)&xs[q] = *(const float4*)(xr + q);
#pragma unroll
  for (int t = 0; t < NT; ++t) {
    acc[t].x = fmaf(xs[t], wv.x, acc[t].x);
    acc[t].y = fmaf(xs[t], wv.y, acc[t].y);
  }
}

// 256 rows, depth-16 float2 weight ring (vmcnt only); x from LDS broadcast.
template <int NT>
__device__ __forceinline__ void accum256_f2(float2* __restrict__ acc,
                                            const float* __restrict__ wp,
                                            const float* __restrict__ xr) {
  float2 ring[16];
#pragma unroll
  for (int k = 0; k < 16; ++k) ring[k] = *(const float2*)(wp + (size_t)k * 4096);
  for (int i0 = 0; i0 + 16 < 256; i0 += 16) {
#pragma unroll
    for (int k = 0; k < 16; ++k) {
      float2 wv = ring[k];
      ring[k] = *(const float2*)(wp + (size_t)(i0 + 16 + k) * 4096);
      fma_row2<NT>(acc, xr + (size_t)(i0 + k) * NT, wv);
    }
  }
#pragma unroll
  for (int k = 0; k < 16; ++k)
    fma_row2<NT>(acc, xr + (size_t)(240 + k) * NT, ring[k]);
}

// Stage 1024 rows x NT floats from [row][16]-strided src into packed LDS.
template <int NT>
__device__ __forceinline__ void stageT(float* __restrict__ lx,
                                       const float* __restrict__ src, int tid) {
  const float4* s4 = (const float4*)src;
  float4* d4 = (float4*)lx;
#pragma unroll
  for (int k = 0; k < NT; ++k) {
    int q = k * 256 + tid;
    int row = q / (NT / 4);
    int part = q & ((NT / 4) - 1);
    d4[q] = s4[row * 4 + part];
  }
}

// Same but fuses g = silu(h1) * h3 during staging.
template <int NT>
__device__ __forceinline__ void stage_silu(float* __restrict__ lx,
                                           const float* __restrict__ h1p,
                                           const float* __restrict__ h3p, int tid) {
  const float4* a4 = (const float4*)h1p;
  const float4* b4 = (const float4*)h3p;
  float4* d4 = (float4*)lx;
#pragma unroll
  for (int k = 0; k < NT; ++k) {
    int q = k * 256 + tid;
    int row = q / (NT / 4);
    int part = q & ((NT / 4) - 1);
    float4 a = a4[row * 4 + part];
    float4 b = b4[row * 4 + part];
    float4 g;
    g.x = (a.x / (1.f + __expf(-a.x))) * b.x;
    g.y = (a.y / (1.f + __expf(-a.y))) * b.y;
    g.z = (a.z / (1.f + __expf(-a.z))) * b.z;
    g.w = (a.w / (1.f + __expf(-a.w))) * b.w;
    d4[q] = g;
  }
}

// --------------------------------------------------------------- passB ----
// Block: one matrix, 128 f-cols (float2/lane), all 4096 h-rows; 4 waves x
// 256-row pieces per 1024-row staged chunk. LDS reduce, plain stores.
template <int NT>
__device__ __forceinline__ void passB_body(const float* __restrict__ Wm,
                                           const float* __restrict__ xsrc,
                                           float* __restrict__ segbase,
                                           float* __restrict__ lx, int tid) {
  int l = tid & 63;
  int w = tid >> 6;
  float2 acc[NT];
#pragma unroll
  for (int t = 0; t < NT; ++t) acc[t] = make_float2(0.f, 0.f);
  for (int ch = 0; ch < 4; ++ch) {
    __syncthreads();
    stageT<NT>(lx, xsrc + (size_t)(ch * 1024) * TSEG, tid);
    __syncthreads();
    accum256_f2<NT>(acc, Wm + (size_t)(ch * 1024 + w * 256) * FF + 2 * l,
                    lx + (size_t)(w * 256) * NT);
  }
  __syncthreads();
  float2* red = (float2*)lx;
#pragma unroll
  for (int t = 0; t < NT; ++t) red[(t * 4 + w) * 64 + l] = acc[t];
  __syncthreads();
  constexpr int TH = NT / 2;
  int col_off = tid & 127;
  int half = tid >> 7;
  int lp = col_off >> 1;
  int comp = col_off & 1;
  float v[TH];
#pragma unroll
  for (int j = 0; j < TH; ++j) {
    int t = half * TH + j;
    float sum = 0.f;
#pragma unroll
    for (int w4 = 0; w4 < 4; ++w4)
      sum += lx[(((t * 4 + w4) * 64 + lp) << 1) + comp];
    v[j] = sum;
  }
  float* seg = segbase + (size_t)col_off * TSEG + half * TH;
#pragma unroll
  for (int q = 0; q < TH; q += 4) *(float4*)(seg + q) = *(const float4*)&v[q];
}

__global__ __launch_bounds__(256) void passB6_kernel(const float* __restrict__ W1,
                                                     const float* __restrict__ W3,
                                                     const float* __restrict__ xseg,
                                                     float* __restrict__ h1seg,
                                                     float* __restrict__ h3seg,
                                                     const int* __restrict__ cnt,
                                                     const int* __restrict__ ord) {
  __shared__ float lx[1024 * TSEG];  // 64 KB
  int gy = blockIdx.y;
  int s = ord[gy >> 1];
  int mat = gy & 1;
  int c = cnt[s];
  if (c == 0) return;
  int e = s >> 1;
  int colbase = blockIdx.x * 128;
  const float* Wm = (mat ? W3 : W1) + (size_t)e * HH * FF + colbase;
  const float* xsrc = xseg + (size_t)s * HH * TSEG;
  float* segbase = (mat ? h3seg : h1seg) + ((size_t)s * FF + colbase) * TSEG;
  if (c <= 8)
    passB_body<8>(Wm, xsrc, segbase, lx, threadIdx.x);
  else
    passB_body<16>(Wm, xsrc, segbase, lx, threadIdx.x);
}

// --------------------------------------------------------------- passC ----
// Block: 128 h-cols, rows [z*2048,+2048) of W2; silu fused in staging;
// epilogue reduce + weighted atomics into out (<=4 adds/element).
template <int NT>
__device__ __forceinline__ void passC_body(const float* __restrict__ Wm,
                                           const float* __restrict__ h1src,
                                           const float* __restrict__ h3src,
                                           float* __restrict__ out,
                                           const int* __restrict__ stok,
                                           const float* __restrict__ swt,
                                           int c, int colbase,
                                           float* __restrict__ lx, int tid) {
  int l = tid & 63;
  int w = tid >> 6;
  float2 acc[NT];
#pragma unroll
  for (int t = 0; t < NT; ++t) acc[t] = make_float2(0.f, 0.f);
  for (int ch = 0; ch < 2; ++ch) {
    __syncthreads();
    stage_silu<NT>(lx, h1src + (size_t)(ch * 1024) * TSEG,
                   h3src + (size_t)(ch * 1024) * TSEG, tid);
    __syncthreads();
    accum256_f2<NT>(acc, Wm + (size_t)(ch * 1024 + w * 256) * HH + 2 * l,
                    lx + (size_t)(w * 256) * NT);
  }
  __syncthreads();
  float2* red = (float2*)lx;
#pragma unroll
  for (int t = 0; t < NT; ++t) red[(t * 4 + w) * 64 + l] = acc[t];
  __syncthreads();
  constexpr int TH = NT / 2;
  int col_off = tid & 127;
  int half = tid >> 7;
  int lp = col_off >> 1;
  int comp = col_off & 1;
  float* op = out + colbase + col_off;
#pragma unroll
  for (int j = 0; j < TH; ++j) {
    int t = half * TH + j;
    if (t < c) {
      float sum = 0.f;
#pragma unroll
      for (int w4 = 0; w4 < 4; ++w4)
        sum += lx[(((t * 4 + w4) * 64 + lp) << 1) + comp];
      atomicAdd(op + (size_t)stok[t] * HH, swt[t] * sum);
    }
  }
}

__global__ __launch_bounds__(256) void passC6_kernel(const float* __restrict__ W2,
                                                     const float* __restrict__ h1seg,
                                                     const float* __restrict__ h3seg,
                                                     const int* __restrict__ cnt,
                                                     const int* __restrict__ tok,
                                                     const float* __restrict__ wts,
                                                     const int* __restrict__ ord,
                                                     float* __restrict__ out) {
  __shared__ float lx[1024 * TSEG];  // 64 KB
  __shared__ int stok[TSEG];
  __shared__ float swt[TSEG];
  int gy = blockIdx.y;
  int s = ord[gy >> 1];
  int z = gy & 1;
  int c = cnt[s];
  if (c == 0) return;
  int e = s >> 1;
  int colbase = blockIdx.x * 128;
  if (threadIdx.x < TSEG) {
    stok[threadIdx.x] = tok[s * TSEG + threadIdx.x];
    swt[threadIdx.x] = wts[s * TSEG + threadIdx.x];
  }
  const float* Wm = W2 + (size_t)e * FF * HH + (size_t)(z * 2048) * HH + colbase;
  const float* h1src = h1seg + ((size_t)s * FF + z * 2048) * TSEG;
  const float* h3src = h3seg + ((size_t)s * FF + z * 2048) * TSEG;
  if (c <= 8)
    passC_body<8>(Wm, h1src, h3src, out, stok, swt, c, colbase, lx, threadIdx.x);
  else
    passC_body<16>(Wm, h1src, h3src, out, stok, swt, c, colbase, lx, threadIdx.x);
}

// -------------------------------------------------------------- launch ----
extern "C" void kernel_launch(void* const* d_in, const int* in_sizes, int n_in,
                              void* d_out, int out_size, void* d_ws, size_t ws_size,
                              hipStream_t stream) {
  const float* x  = (const float*)d_in[0];
  const float* Wg = (const float*)d_in[1];
  const float* W1 = (const float*)d_in[2];
  const float* W3 = (const float*)d_in[3];
  const float* W2 = (const float*)d_in[4];
  float* out = (float*)d_out;

  char* ws = (char*)d_ws;
  float* logits = (float*)ws;                 // 256 f32
  int*   cnt    = (int*)(ws + 1024);          // 16 i32
  int*   tok    = (int*)(ws + 1088);          // 256 i32
  float* wts    = (float*)(ws + 2112);        // 256 f32
  int*   ord    = (int*)(ws + 3136);          // 16 i32
  float* xseg   = (float*)(ws + 4096);                 // 4 MB
  float* h1seg  = xseg + (size_t)NSLOT * HH * TSEG;    // 4 MB
  float* h3seg  = h1seg + (size_t)NSLOT * FF * TSEG;   // 4 MB

  hipMemsetAsync(d_out, 0, (size_t)out_size * sizeof(float), stream);
  gate_kernel<<<BB, 256, 0, stream>>>(x, Wg, logits);
  route_kernel<<<1, 64, 0, stream>>>(logits, cnt, tok, wts, ord);
  buildx_kernel<<<dim3(HH / 256, NSLOT), 256, 0, stream>>>(x, cnt, tok, xseg);
  passB6_kernel<<<dim3(FF / 128, NSLOT * 2), 256, 0, stream>>>(W1, W3, xseg, h1seg, h3seg, cnt, ord);
  passC6_kernel<<<dim3(HH / 128, NSLOT * 2), 256, 0, stream>>>(W2, h1seg, h3seg, cnt, tok, wts, ord, out);
}

// Round 7
// 362.271 us; speedup vs baseline: 2.7205x; 1.1129x over previous
//
#include <hip/hip_runtime.h>
#include <cstdint>

#define BB 32
#define HH 4096
#define FF 4096
#define EE 8
#define NSLOT 16   // 8 experts x 2 slots of <=16 tokens
#define TSEG 16
#define CH 512     // rows staged per chunk
#define RSTR 36    // reduce stride (floats, 16B-aligned)

// ---------------------------------------------------------------- gate ----
__global__ __launch_bounds__(256) void gate_kernel(const float* __restrict__ x,
                                                   const float* __restrict__ Wg,
                                                   float* __restrict__ logits) {
  int b = blockIdx.x;
  int tid = threadIdx.x;
  float acc[EE];
#pragma unroll
  for (int e = 0; e < EE; ++e) acc[e] = 0.f;
  const float* xb = x + (size_t)b * HH;
  for (int h = tid; h < HH; h += 256) {
    float xv = xb[h];
    const float4* wg = (const float4*)(Wg + (size_t)h * EE);
    float4 w0 = wg[0], w1 = wg[1];
    acc[0] = fmaf(xv, w0.x, acc[0]);
    acc[1] = fmaf(xv, w0.y, acc[1]);
    acc[2] = fmaf(xv, w0.z, acc[2]);
    acc[3] = fmaf(xv, w0.w, acc[3]);
    acc[4] = fmaf(xv, w1.x, acc[4]);
    acc[5] = fmaf(xv, w1.y, acc[5]);
    acc[6] = fmaf(xv, w1.z, acc[6]);
    acc[7] = fmaf(xv, w1.w, acc[7]);
  }
#pragma unroll
  for (int off = 32; off > 0; off >>= 1) {
#pragma unroll
    for (int e = 0; e < EE; ++e) acc[e] += __shfl_down(acc[e], off, 64);
  }
  __shared__ float part[4][EE];
  if ((tid & 63) == 0) {
#pragma unroll
    for (int e = 0; e < EE; ++e) part[tid >> 6][e] = acc[e];
  }
  __syncthreads();
  if (tid < EE) {
    logits[(size_t)b * EE + tid] =
        part[0][tid] + part[1][tid] + part[2][tid] + part[3][tid];
  }
}

// --------------------------------------------------------------- route ----
__global__ void route_kernel(const float* __restrict__ logits,
                             int* __restrict__ cnt,
                             int* __restrict__ tok,
                             float* __restrict__ wts,
                             int* __restrict__ ord) {
  if (threadIdx.x != 0 || blockIdx.x != 0) return;
  int e0[BB], e1[BB];
  float p0[BB], p1[BB];
  for (int b = 0; b < BB; ++b) {
    const float* L = logits + (size_t)b * EE;
    int i0 = 0;
    float v0 = L[0];
    for (int e = 1; e < EE; ++e) {
      float v = L[e];
      if (v > v0) { v0 = v; i0 = e; }
    }
    int i1 = (i0 == 0) ? 1 : 0;
    float v1 = L[i1];
    for (int e = 0; e < EE; ++e) {
      if (e == i0) continue;
      float v = L[e];
      if (v > v1) { v1 = v; i1 = e; }
    }
    float p = 1.f / (1.f + __expf(v1 - v0));
    e0[b] = i0; e1[b] = i1; p0[b] = p; p1[b] = 1.f - p;
  }
  for (int s = 0; s < NSLOT; ++s) {
    cnt[s] = 0;
    for (int t = 0; t < TSEG; ++t) { tok[s * TSEG + t] = 0; wts[s * TSEG + t] = 0.f; }
  }
  for (int e = 0; e < EE; ++e) {
    int c = 0;
    for (int b = 0; b < BB; ++b) {
      float w = 0.f;
      int sel = 0;
      if (e0[b] == e) { w = p0[b]; sel = 1; }
      else if (e1[b] == e) { w = p1[b]; sel = 1; }
      if (sel) {
        int s = e * 2 + (c >> 4);
        int t = c & 15;
        tok[s * TSEG + t] = b;
        wts[s * TSEG + t] = w;
        cnt[s] = t + 1;
        ++c;
      }
    }
  }
  int na = 0;
  for (int s = 0; s < NSLOT; ++s) if (cnt[s] > 0) ord[na++] = s;
  for (int s = 0; s < NSLOT; ++s) if (cnt[s] == 0) ord[na++] = s;
}

// -------------------------------------------------------------- buildx ----
__global__ __launch_bounds__(256) void buildx_kernel(const float* __restrict__ x,
                                                     const int* __restrict__ cnt,
                                                     const int* __restrict__ tok,
                                                     float* __restrict__ xseg) {
  int s = blockIdx.y;
  int c = cnt[s];
  if (c == 0) return;
  int tid = threadIdx.x;
  int t = tid & 15;
  int hoff = tid >> 4;
  int tk = tok[s * TSEG + t];
  bool act = t < c;
  int hbase = blockIdx.x * 256;
#pragma unroll
  for (int i = 0; i < 16; ++i) {
    int h = hbase + i * 16 + hoff;
    float v = act ? x[(size_t)tk * HH + h] : 0.f;
    xseg[((size_t)s * HH + h) * TSEG + t] = v;
  }
}

// ----------------------------------------------------------- core math ----
// Lane covers 4 cols (float4 weight) x 8 tokens (half-wave split).
// 128 rows per call, depth-8 float4 weight ring (vmcnt only); xs = 2 b128
// broadcast reads per row from LDS (lgkmcnt).
__device__ __forceinline__ void fma8(float4* __restrict__ acc,
                                     const float* __restrict__ xr, float4 wv) {
  float xs[8];
  *(float4*)&xs[0] = *(const float4*)(xr);
  *(float4*)&xs[4] = *(const float4*)(xr + 4);
#pragma unroll
  for (int t = 0; t < 8; ++t) {
    acc[t].x = fmaf(xs[t], wv.x, acc[t].x);
    acc[t].y = fmaf(xs[t], wv.y, acc[t].y);
    acc[t].z = fmaf(xs[t], wv.z, acc[t].z);
    acc[t].w = fmaf(xs[t], wv.w, acc[t].w);
  }
}

__device__ __forceinline__ void accum128(float4* __restrict__ acc,
                                         const float4* __restrict__ wp4,
                                         const float* __restrict__ lxw,
                                         int half8) {
  float4 ring[8];
#pragma unroll
  for (int k = 0; k < 8; ++k) ring[k] = wp4[(size_t)k * 1024];
  for (int i0 = 0; i0 + 8 < 128; i0 += 8) {
#pragma unroll
    for (int k = 0; k < 8; ++k) {
      float4 wv = ring[k];
      ring[k] = wp4[(size_t)(i0 + 8 + k) * 1024];
      fma8(acc, lxw + (i0 + k) * TSEG + half8, wv);
    }
  }
#pragma unroll
  for (int k = 0; k < 8; ++k)
    fma8(acc, lxw + (120 + k) * TSEG + half8, ring[k]);
}

// Stage CH=512 rows x 16 floats (linear 32 KB copy).
__device__ __forceinline__ void stage512(float* __restrict__ lx,
                                         const float* __restrict__ src, int tid) {
  const float4* s4 = (const float4*)src;
  float4* d4 = (float4*)lx;
#pragma unroll
  for (int k = 0; k < 8; ++k) d4[k * 256 + tid] = s4[k * 256 + tid];
}

// Same with fused g = silu(h1) * h3.
__device__ __forceinline__ void stage_silu512(float* __restrict__ lx,
                                              const float* __restrict__ h1p,
                                              const float* __restrict__ h3p, int tid) {
  const float4* a4 = (const float4*)h1p;
  const float4* b4 = (const float4*)h3p;
  float4* d4 = (float4*)lx;
#pragma unroll
  for (int k = 0; k < 8; ++k) {
    float4 a = a4[k * 256 + tid];
    float4 b = b4[k * 256 + tid];
    float4 g;
    g.x = (a.x / (1.f + __expf(-a.x))) * b.x;
    g.y = (a.y / (1.f + __expf(-a.y))) * b.y;
    g.z = (a.z / (1.f + __expf(-a.z))) * b.z;
    g.w = (a.w / (1.f + __expf(-a.w))) * b.w;
    d4[k * 256 + tid] = g;
  }
}

// Write per-lane acc (4 cols x 8 toks) into the reduce scratch.
__device__ __forceinline__ void red_write(float* __restrict__ lds,
                                          const float4* __restrict__ acc, int tid) {
  int l = tid & 63;
  int w = tid >> 6;
  float tmp[32];
#pragma unroll
  for (int t = 0; t < 8; ++t) {
    tmp[t] = acc[t].x;
    tmp[8 + t] = acc[t].y;
    tmp[16 + t] = acc[t].z;
    tmp[24 + t] = acc[t].w;
  }
  float* rp = lds + (size_t)(w * 64 + l) * RSTR;
#pragma unroll
  for (int q = 0; q < 32; q += 4) *(float4*)(rp + q) = *(const float4*)&tmp[q];
}

// Reader: thread = (col 0..127, half 0..1); sums 4 waves for 8 tokens.
__device__ __forceinline__ void red_read(const float* __restrict__ lds,
                                         float* __restrict__ v, int tid) {
  int col = tid & 127;
  int half = tid >> 7;
  int base = (half * 32 + (col >> 2)) * RSTR + (col & 3) * 8;
#pragma unroll
  for (int t = 0; t < 8; ++t) {
    float sum = 0.f;
#pragma unroll
    for (int w = 0; w < 4; ++w) sum += lds[w * 64 * RSTR + base + t];
    v[t] = sum;
  }
}

// --------------------------------------------------------------- passB ----
// Block: one matrix, 128 f-cols, all 4096 h-rows; 8 chunks of 512 rows,
// 4 waves x 128 rows each. LDS reduce, plain stores.
__global__ __launch_bounds__(256) void passB7_kernel(const float* __restrict__ W1,
                                                     const float* __restrict__ W3,
                                                     const float* __restrict__ xseg,
                                                     float* __restrict__ h1seg,
                                                     float* __restrict__ h3seg,
                                                     const int* __restrict__ cnt,
                                                     const int* __restrict__ ord) {
  __shared__ float lds[4 * 64 * RSTR];  // 36.9 KB (>= 32 KB stage)
  int gy = blockIdx.y;
  int s = ord[gy >> 1];
  int mat = gy & 1;
  int c = cnt[s];
  if (c == 0) return;
  int e = s >> 1;
  int tid = threadIdx.x;
  int l = tid & 63;
  int w = tid >> 6;
  int colbase = blockIdx.x * 128;
  const float* Wm = (mat ? W3 : W1) + (size_t)e * HH * FF + colbase + (l & 31) * 4;
  const float* xsrc = xseg + (size_t)s * HH * TSEG;
  int half8 = (l >> 5) * 8;
  float4 acc[8];
#pragma unroll
  for (int t = 0; t < 8; ++t) acc[t] = make_float4(0.f, 0.f, 0.f, 0.f);
  for (int ch = 0; ch < HH / CH; ++ch) {
    __syncthreads();
    stage512(lds, xsrc + (size_t)(ch * CH) * TSEG, tid);
    __syncthreads();
    const float4* wp4 = (const float4*)(Wm + (size_t)(ch * CH + w * 128) * FF);
    accum128(acc, wp4, lds + (w * 128) * TSEG, half8);
  }
  __syncthreads();
  red_write(lds, acc, tid);
  __syncthreads();
  float v[8];
  red_read(lds, v, tid);
  int col = tid & 127;
  int half = tid >> 7;
  float* seg = (mat ? h3seg : h1seg) +
               ((size_t)s * FF + colbase + col) * TSEG + half * 8;
  *(float4*)(seg) = *(const float4*)&v[0];
  *(float4*)(seg + 4) = *(const float4*)&v[4];
}

// --------------------------------------------------------------- passC ----
// Block: 128 h-cols, rows [z*2048,+2048) of W2 (4 chunks); silu fused in
// staging; epilogue reduce + weighted atomics (<=4 adds/element).
__global__ __launch_bounds__(256) void passC7_kernel(const float* __restrict__ W2,
                                                     const float* __restrict__ h1seg,
                                                     const float* __restrict__ h3seg,
                                                     const int* __restrict__ cnt,
                                                     const int* __restrict__ tok,
                                                     const float* __restrict__ wts,
                                                     const int* __restrict__ ord,
                                                     float* __restrict__ out) {
  __shared__ float lds[4 * 64 * RSTR];
  __shared__ int stok[TSEG];
  __shared__ float swt[TSEG];
  int gy = blockIdx.y;
  int s = ord[gy >> 1];
  int z = gy & 1;
  int c = cnt[s];
  if (c == 0) return;
  int e = s >> 1;
  int tid = threadIdx.x;
  int l = tid & 63;
  int w = tid >> 6;
  int colbase = blockIdx.x * 128;
  if (tid < TSEG) {
    stok[tid] = tok[s * TSEG + tid];
    swt[tid] = wts[s * TSEG + tid];
  }
  const float* Wm = W2 + (size_t)e * FF * HH + (size_t)(z * 2048) * HH +
                    colbase + (l & 31) * 4;
  const float* h1src = h1seg + ((size_t)s * FF + z * 2048) * TSEG;
  const float* h3src = h3seg + ((size_t)s * FF + z * 2048) * TSEG;
  int half8 = (l >> 5) * 8;
  float4 acc[8];
#pragma unroll
  for (int t = 0; t < 8; ++t) acc[t] = make_float4(0.f, 0.f, 0.f, 0.f);
  for (int ch = 0; ch < 4; ++ch) {
    __syncthreads();
    stage_silu512(lds, h1src + (size_t)(ch * CH) * TSEG,
                  h3src + (size_t)(ch * CH) * TSEG, tid);
    __syncthreads();
    const float4* wp4 = (const float4*)(Wm + (size_t)(ch * CH + w * 128) * HH);
    accum128(acc, wp4, lds + (w * 128) * TSEG, half8);
  }
  __syncthreads();
  red_write(lds, acc, tid);
  __syncthreads();
  float v[8];
  red_read(lds, v, tid);
  int col = tid & 127;
  int half = tid >> 7;
  float* op = out + colbase + col;
#pragma unroll
  for (int t = 0; t < 8; ++t) {
    int tt = half * 8 + t;
    if (tt < c) atomicAdd(op + (size_t)stok[tt] * HH, swt[tt] * v[t]);
  }
}

// -------------------------------------------------------------- launch ----
extern "C" void kernel_launch(void* const* d_in, const int* in_sizes, int n_in,
                              void* d_out, int out_size, void* d_ws, size_t ws_size,
                              hipStream_t stream) {
  const float* x  = (const float*)d_in[0];
  const float* Wg = (const float*)d_in[1];
  const float* W1 = (const float*)d_in[2];
  const float* W3 = (const float*)d_in[3];
  const float* W2 = (const float*)d_in[4];
  float* out = (float*)d_out;

  char* ws = (char*)d_ws;
  float* logits = (float*)ws;                 // 256 f32
  int*   cnt    = (int*)(ws + 1024);          // 16 i32
  int*   tok    = (int*)(ws + 1088);          // 256 i32
  float* wts    = (float*)(ws + 2112);        // 256 f32
  int*   ord    = (int*)(ws + 3136);          // 16 i32
  float* xseg   = (float*)(ws + 4096);                 // 4 MB
  float* h1seg  = xseg + (size_t)NSLOT * HH * TSEG;    // 4 MB
  float* h3seg  = h1seg + (size_t)NSLOT * FF * TSEG;   // 4 MB

  hipMemsetAsync(d_out, 0, (size_t)out_size * sizeof(float), stream);
  gate_kernel<<<BB, 256, 0, stream>>>(x, Wg, logits);
  route_kernel<<<1, 64, 0, stream>>>(logits, cnt, tok, wts, ord);
  buildx_kernel<<<dim3(HH / 256, NSLOT), 256, 0, stream>>>(x, cnt, tok, xseg);
  passB7_kernel<<<dim3(FF / 128, NSLOT * 2), 256, 0, stream>>>(W1, W3, xseg, h1seg, h3seg, cnt, ord);
  passC7_kernel<<<dim3(HH / 128, NSLOT * 2), 256, 0, stream>>>(W2, h1seg, h3seg, cnt, tok, wts, ord, out);
}